// Round 1
// baseline (324.596 us; speedup 1.0000x reference)
//
#include <hip/hip_runtime.h>

// Problem constants (from reference setup_inputs)
#define BB 4
#define TT 16
#define HH 512
#define WW 512

// Tile geometry: block = 256 threads, tile = 128 wide x 64 tall output px.
// Thread = 8 wide x 4 tall register tile. Thread grid: 16 tx x 16 ty.
#define TW 128
#define TH 64
#define HALO 8
#define LR (TH + 2 * HALO)   // 80 LDS rows
#define LC (TW + 2 * HALO)   // 144 LDS cols (floats)

__device__ __forceinline__ int reflect_idx(int q, int n) {
    // jnp.pad 'reflect': -1 -> 1, n -> n-2 (single reflection suffices, halo=8 << 512)
    q = abs(q);
    if (q >= n) q = 2 * n - 2 - q;
    return q;
}

// Pack: pw[c*75 + bidx*25 + i*5 + j] = scale[bidx] * w_bidx[c][i][j]; pw[225] = sum scale*bias
__global__ void pack_weights(const float* __restrict__ w1, const float* __restrict__ b1,
                             const float* __restrict__ w2, const float* __restrict__ b2,
                             const float* __restrict__ w3, const float* __restrict__ b3,
                             const float* __restrict__ sa, const float* __restrict__ sb,
                             const float* __restrict__ sc, float* __restrict__ pw) {
    int tid = threadIdx.x;
    float s0 = sa[0], s1 = sb[0], s2 = sc[0];
    for (int idx = tid; idx < 225; idx += blockDim.x) {
        int c = idx / 75;
        int r = idx % 75;
        int bidx = r / 25;
        int t = r % 25;
        float sv = (bidx == 0) ? s0 : (bidx == 1) ? s1 : s2;
        const float* wp = (bidx == 0) ? w1 : (bidx == 1) ? w2 : w3;
        pw[idx] = sv * wp[c * 25 + t];
    }
    if (tid == 0) pw[225] = s0 * b1[0] + s1 * b2[0] + s2 * b3[0];
}

// One fused denoise block: out = tanh(sum_d scale_d * conv_d(triplet(x))) for all (b,t,h,w)
__global__ __launch_bounds__(256) void conv_block(const float* __restrict__ x,
                                                  float* __restrict__ out,
                                                  const float* __restrict__ pw) {
    __shared__ float smem[LR * LC];

    const int bt = blockIdx.z;            // b*T + t
    const int t  = bt % TT;
    const int h0 = blockIdx.y * TH;
    const int w0 = blockIdx.x * TW;
    const int tid = threadIdx.x;
    const int tx = tid & 15;              // 16 thread cols
    const int ty = tid >> 4;              // 16 thread rows
    const int oc = tx * 8;                // tile-local col of first output px
    const int orow = ty * 4;              // tile-local row of first output px

    const int tprev = (t == 0) ? 1 : t - 1;
    const int tnext = (t == TT - 1) ? TT - 2 : t + 1;
    const int bbase = (bt / TT) * TT;
    const size_t fstride = (size_t)HH * WW;
    const float* frp = x + (size_t)(bbase + tprev) * fstride;
    const float* frc = x + (size_t)bt * fstride;
    const float* frn = x + (size_t)(bbase + tnext) * fstride;

    const float bias = pw[225];
    float acc[4][8];
#pragma unroll
    for (int p = 0; p < 4; ++p)
#pragma unroll
        for (int q = 0; q < 8; ++q) acc[p][q] = bias;

    const bool interior = (h0 >= HALO) && (h0 + TH + HALO <= HH) &&
                          (w0 >= HALO) && (w0 + TW + HALO <= WW);

#pragma unroll 1
    for (int c = 0; c < 3; ++c) {
        __syncthreads();   // protect smem from previous channel's readers
        const float* src = (c == 0) ? frp : (c == 1) ? frc : frn;

        if (interior) {
            // vectorized staging, rows contiguous in global
            for (int idx = tid; idx < LR * (LC / 4); idx += 256) {
                int row = idx / (LC / 4);
                int c4  = idx % (LC / 4);
                int q_sw = c4 ^ ((row & 4) >> 2);      // word-col XOR (row&4) == quad XOR bit0
                const float4 v = *reinterpret_cast<const float4*>(
                    src + (size_t)(h0 - HALO + row) * WW + (w0 - HALO) + c4 * 4);
                *reinterpret_cast<float4*>(smem + row * LC + q_sw * 4) = v;
            }
        } else {
            for (int idx = tid; idx < LR * LC; idx += 256) {
                int row = idx / LC;
                int col = idx % LC;
                int gh = reflect_idx(h0 - HALO + row, HH);
                int gw = reflect_idx(w0 - HALO + col, WW);
                smem[row * LC + (col ^ (row & 4))] = src[(size_t)gh * WW + gw];
            }
        }
        __syncthreads();

        const float* pwc = pw + c * 75;   // uniform address -> scalar loads

        // Row-streaming over the 20-row window this thread needs
#pragma unroll
        for (int rr = 0; rr < 20; ++rr) {
            const int row = orow + rr;
            float rv[24];
#pragma unroll
            for (int q = 0; q < 6; ++q) {
                int wc = (oc + q * 4) ^ (row & 4);
                const float4 v = *reinterpret_cast<const float4*>(smem + row * LC + wc);
                rv[q * 4 + 0] = v.x; rv[q * 4 + 1] = v.y;
                rv[q * 4 + 2] = v.z; rv[q * 4 + 3] = v.w;
            }
#pragma unroll
            for (int bidx = 0; bidx < 3; ++bidx) {
                const int d = 1 << bidx;   // dilation 1,2,4
#pragma unroll
                for (int i = 0; i < 5; ++i) {
                    const int pr = rr - 8 - (i - 2) * d;   // output row (0..3) this tap feeds
                    if (pr < 0 || pr > 3) continue;        // folded at compile time
#pragma unroll
                    for (int j = 0; j < 5; ++j) {
                        const float wv = pwc[bidx * 25 + i * 5 + j];
                        const int cb = 8 + (j - 2) * d;
#pragma unroll
                        for (int q = 0; q < 8; ++q)
                            acc[pr][q] = fmaf(wv, rv[cb + q], acc[pr][q]);
                    }
                }
            }
        }
    }

    // Epilogue: tanh + store
    float* dst = out + (size_t)bt * fstride + (size_t)h0 * WW + w0;
#pragma unroll
    for (int p = 0; p < 4; ++p) {
#pragma unroll
        for (int q = 0; q < 8; ++q) {
            float v = acc[p][q];
            float e = __expf(2.0f * v);
            acc[p][q] = 1.0f - 2.0f / (e + 1.0f);   // tanh(v), exact at +/-inf
        }
        float4 v0 = make_float4(acc[p][0], acc[p][1], acc[p][2], acc[p][3]);
        float4 v1 = make_float4(acc[p][4], acc[p][5], acc[p][6], acc[p][7]);
        float* rowp = dst + (size_t)(orow + p) * WW + oc;
        *reinterpret_cast<float4*>(rowp) = v0;
        *reinterpret_cast<float4*>(rowp + 4) = v1;
    }
}

extern "C" void kernel_launch(void* const* d_in, const int* in_sizes, int n_in,
                              void* d_out, int out_size, void* d_ws, size_t ws_size,
                              hipStream_t stream) {
    const float* x = (const float*)d_in[0];
    // d_in order: x, blk1_{w1,b1,w2,b2,w3,b3,a,b,c}, blk2_{...}
    float* pw1 = (float*)d_ws;                       // 226 floats
    float* pw2 = (float*)d_ws + 256;                 // 226 floats
    float* y   = (float*)((char*)d_ws + 4096);       // intermediate, 64 MB
    float* z   = (float*)d_out;

    pack_weights<<<1, 256, 0, stream>>>((const float*)d_in[1], (const float*)d_in[2],
                                        (const float*)d_in[3], (const float*)d_in[4],
                                        (const float*)d_in[5], (const float*)d_in[6],
                                        (const float*)d_in[7], (const float*)d_in[8],
                                        (const float*)d_in[9], pw1);
    pack_weights<<<1, 256, 0, stream>>>((const float*)d_in[10], (const float*)d_in[11],
                                        (const float*)d_in[12], (const float*)d_in[13],
                                        (const float*)d_in[14], (const float*)d_in[15],
                                        (const float*)d_in[16], (const float*)d_in[17],
                                        (const float*)d_in[18], pw2);

    dim3 grid(WW / TW, HH / TH, BB * TT);
    conv_block<<<grid, 256, 0, stream>>>(x, y, pw1);
    conv_block<<<grid, 256, 0, stream>>>(y, z, pw2);
}

// Round 2
// 309.359 us; speedup vs baseline: 1.0493x; 1.0493x over previous
//
#include <hip/hip_runtime.h>
#include <hip/hip_fp16.h>

// Problem constants
#define BB 4
#define TT 16
#define HH 512
#define WW 512

// Tile geometry: 256 threads, output tile 128 wide x 64 tall.
// Thread = 8 wide x 4 tall. Thread grid 16 tx x 16 ty.
#define TW 128
#define TH 64
#define HALO 8
#define SR (TH + 2 * HALO)    // 80 staged rows
#define SC (TW + 2 * HALO)    // 144 staged cols (halves actually used)
#define LCH 152               // padded row stride in halves (304 B, 16B-aligned)
#define CHS (SR * LCH)        // 12160 halves per channel buffer

__device__ __forceinline__ int reflect_idx(int q, int n) {
    q = abs(q);
    if (q >= n) q = 2 * n - 2 - q;
    return q;
}

// pw[c*75 + bidx*25 + i*5 + j] = scale[bidx]*w_bidx[c][i][j]; pw[225] = sum scale*bias
__global__ void pack_weights(const float* __restrict__ w1, const float* __restrict__ b1,
                             const float* __restrict__ w2, const float* __restrict__ b2,
                             const float* __restrict__ w3, const float* __restrict__ b3,
                             const float* __restrict__ sa, const float* __restrict__ sb,
                             const float* __restrict__ sc, float* __restrict__ pw) {
    int tid = threadIdx.x;
    float s0 = sa[0], s1 = sb[0], s2 = sc[0];
    for (int idx = tid; idx < 225; idx += blockDim.x) {
        int c = idx / 75;
        int r = idx % 75;
        int bidx = r / 25;
        int t = r % 25;
        float sv = (bidx == 0) ? s0 : (bidx == 1) ? s1 : s2;
        const float* wp = (bidx == 0) ? w1 : (bidx == 1) ? w2 : w3;
        pw[idx] = sv * wp[c * 25 + t];
    }
    if (tid == 0) pw[225] = s0 * b1[0] + s1 * b2[0] + s2 * b3[0];
}

__device__ __forceinline__ void unpack8(uint4 u, float* rf) {
    const __half2* h = reinterpret_cast<const __half2*>(&u);
#pragma unroll
    for (int i = 0; i < 4; ++i) {
        rf[2 * i]     = __low2float(h[i]);   // fpext f16 -> f32: fuses into v_fma_mix
        rf[2 * i + 1] = __high2float(h[i]);
    }
}

__global__ __launch_bounds__(256, 2) void conv_block(const float* __restrict__ x,
                                                     float* __restrict__ out,
                                                     const float* __restrict__ pw) {
    __shared__ __half lds[3 * CHS];   // 72,960 B -> 2 blocks/CU

    const int bt = blockIdx.z;
    const int t  = bt % TT;
    const int h0 = blockIdx.y * TH;
    const int w0 = blockIdx.x * TW;
    const int tid = threadIdx.x;
    const int tx = tid & 15;
    const int ty = tid >> 4;
    const int oc = tx * 8;
    const int orow = ty * 4;

    const int tprev = (t == 0) ? 1 : t - 1;
    const int tnext = (t == TT - 1) ? TT - 2 : t + 1;
    const int bbase = (bt / TT) * TT;
    const size_t fs = (size_t)HH * WW;
    const float* frp = x + (size_t)(bbase + tprev) * fs;
    const float* frc = x + (size_t)bt * fs;
    const float* frn = x + (size_t)(bbase + tnext) * fs;

    // ---- Stage all 3 channels into fp16 LDS (single barrier after) ----
#pragma unroll
    for (int ch = 0; ch < 3; ++ch) {
        const float* src = (ch == 0) ? frp : (ch == 1) ? frc : frn;  // compile-time ch
        for (int k = tid; k < SR * (SC / 4); k += 256) {
            int row = k / (SC / 4);
            int c4  = k - row * (SC / 4);
            int gh = reflect_idx(h0 - HALO + row, HH);
            int gb = w0 - HALO + c4 * 4;
            __half2 p0, p1;
            if (gb >= 0 && gb + 3 < WW) {
                const float4 v = *reinterpret_cast<const float4*>(src + (size_t)gh * WW + gb);
                p0 = __floats2half2_rn(v.x, v.y);
                p1 = __floats2half2_rn(v.z, v.w);
            } else {
                float a = src[(size_t)gh * WW + reflect_idx(gb + 0, WW)];
                float b = src[(size_t)gh * WW + reflect_idx(gb + 1, WW)];
                float c = src[(size_t)gh * WW + reflect_idx(gb + 2, WW)];
                float d = src[(size_t)gh * WW + reflect_idx(gb + 3, WW)];
                p0 = __floats2half2_rn(a, b);
                p1 = __floats2half2_rn(c, d);
            }
            union { __half2 h2[2]; uint2 u; } cv;
            cv.h2[0] = p0; cv.h2[1] = p1;
            *reinterpret_cast<uint2*>(&lds[ch * CHS + row * LCH + c4 * 4]) = cv.u;
        }
    }

    const float bias = pw[225];
    float acc[4][8];
#pragma unroll
    for (int p = 0; p < 4; ++p)
#pragma unroll
        for (int q = 0; q < 8; ++q) acc[p][q] = bias;

    __syncthreads();

    // ---- Compute: 3 channels, 20 staged rows each, immediate-offset b128 reads ----
#pragma unroll
    for (int ch = 0; ch < 3; ++ch) {
        const __half* rbase = &lds[ch * CHS + orow * LCH + oc];  // one VGPR base per channel
        const float* pwc = pw + ch * 75;                         // uniform -> s_load

#pragma unroll
        for (int rr = 0; rr < 20; ++rr) {
            const uint4 u0 = *reinterpret_cast<const uint4*>(rbase + rr * LCH);
            const uint4 u1 = *reinterpret_cast<const uint4*>(rbase + rr * LCH + 8);
            const uint4 u2 = *reinterpret_cast<const uint4*>(rbase + rr * LCH + 16);
            float rf[24];
            unpack8(u0, rf + 0);
            unpack8(u1, rf + 8);
            unpack8(u2, rf + 16);

#pragma unroll
            for (int bidx = 0; bidx < 3; ++bidx) {
                const int d = 1 << bidx;   // dilation 1,2,4
#pragma unroll
                for (int i = 0; i < 5; ++i) {
                    const int pr = rr - 8 - (i - 2) * d;   // output row fed by this tap row
                    if (pr < 0 || pr > 3) continue;        // compile-time fold
#pragma unroll
                    for (int j = 0; j < 5; ++j) {
                        const float wv = pwc[bidx * 25 + i * 5 + j];
                        const int cb = 8 + (j - 2) * d;
#pragma unroll
                        for (int q = 0; q < 8; ++q)
                            acc[pr][q] = fmaf(wv, rf[cb + q], acc[pr][q]);
                    }
                }
            }
        }
    }

    // ---- Epilogue: tanh + fp32 store ----
    float* dst = out + (size_t)bt * fs + (size_t)h0 * WW + w0;
#pragma unroll
    for (int p = 0; p < 4; ++p) {
#pragma unroll
        for (int q = 0; q < 8; ++q) {
            float v = acc[p][q];
            float e = __expf(2.0f * v);
            acc[p][q] = 1.0f - 2.0f / (e + 1.0f);
        }
        float4 v0 = make_float4(acc[p][0], acc[p][1], acc[p][2], acc[p][3]);
        float4 v1 = make_float4(acc[p][4], acc[p][5], acc[p][6], acc[p][7]);
        float* rowp = dst + (size_t)(orow + p) * WW + oc;
        *reinterpret_cast<float4*>(rowp) = v0;
        *reinterpret_cast<float4*>(rowp + 4) = v1;
    }
}

extern "C" void kernel_launch(void* const* d_in, const int* in_sizes, int n_in,
                              void* d_out, int out_size, void* d_ws, size_t ws_size,
                              hipStream_t stream) {
    const float* x = (const float*)d_in[0];
    float* pw1 = (float*)d_ws;
    float* pw2 = (float*)d_ws + 256;
    float* y   = (float*)((char*)d_ws + 4096);   // intermediate, 64 MB
    float* z   = (float*)d_out;

    pack_weights<<<1, 256, 0, stream>>>((const float*)d_in[1], (const float*)d_in[2],
                                        (const float*)d_in[3], (const float*)d_in[4],
                                        (const float*)d_in[5], (const float*)d_in[6],
                                        (const float*)d_in[7], (const float*)d_in[8],
                                        (const float*)d_in[9], pw1);
    pack_weights<<<1, 256, 0, stream>>>((const float*)d_in[10], (const float*)d_in[11],
                                        (const float*)d_in[12], (const float*)d_in[13],
                                        (const float*)d_in[14], (const float*)d_in[15],
                                        (const float*)d_in[16], (const float*)d_in[17],
                                        (const float*)d_in[18], pw2);

    dim3 grid(WW / TW, HH / TH, BB * TT);
    conv_block<<<grid, 256, 0, stream>>>(x, y, pw1);
    conv_block<<<grid, 256, 0, stream>>>(y, z, pw2);
}